// Round 3
// baseline (1594.229 us; speedup 1.0000x reference)
//
#include <hip/hip_runtime.h>
#include <hip/hip_cooperative_groups.h>
#include <math.h>

namespace cg = cooperative_groups;

// Problem constants (reference: B,N,M,C = 4,4096,4096,256)
#define BB 4
#define BN 4096          // N == M == 4096
constexpr float T2      = 0.04f;                     // DIST_THRESH^2
constexpr float INV_EPS = (float)(1.0 / 0.01000001); // 1/(EPSILON + 1e-8)

__device__ __forceinline__ int cell_of(float x, float y) {
  int cx = (int)(x * 5.0f); cx = cx < 0 ? 0 : (cx > 4 ? 4 : cx);
  int cy = (int)(y * 5.0f); cy = cy < 0 ? 0 : (cy > 4 ? 4 : cy);
  return cy * 5 + cx;
}

// ---------------------------------------------------------------- binning ---
__global__ void k_count(const float* __restrict__ tlocs, const float* __restrict__ slocs,
                        int* __restrict__ counts_t, int* __restrict__ counts_s) {
  int gid = blockIdx.x * 256 + threadIdx.x;       // covers B*(M+N) = 32768
  if (gid < BB * BN) {
    int b = gid >> 12;
    atomicAdd(&counts_t[b * 32 + cell_of(tlocs[gid * 2], tlocs[gid * 2 + 1])], 1);
  } else {
    int g = gid - BB * BN;
    int b = g >> 12;
    atomicAdd(&counts_s[b * 32 + cell_of(slocs[g * 2], slocs[g * 2 + 1])], 1);
  }
}

// Scan 25 cells, scatter indices AND build cell-sorted packs (x, y, 0, valid).
__global__ void k_scan_scatter(const float* __restrict__ tlocs, const float* __restrict__ slocs,
                               const int* __restrict__ tmask, const int* __restrict__ smask,
                               const int* __restrict__ counts_t, const int* __restrict__ counts_s,
                               int* __restrict__ starts_t, int* __restrict__ starts_s,
                               int* __restrict__ perm_t, int* __restrict__ perm_s,
                               float4* __restrict__ t_sorted, float4* __restrict__ s_sorted) {
  const int which = blockIdx.x & 1, b = blockIdx.x >> 1;   // grid = 2*B
  const float* locs = which ? slocs : tlocs;
  const int*   mask = which ? smask : tmask;
  const int* counts = which ? counts_s : counts_t;
  int* starts       = which ? starts_s : starts_t;
  int* perm         = which ? perm_s : perm_t;
  float4* pack      = which ? s_sorted : t_sorted;
  __shared__ int st[26];
  __shared__ int cur[25];
  if (threadIdx.x == 0) {
    int acc = 0;
    for (int c = 0; c < 25; c++) { st[c] = acc; acc += counts[b * 32 + c]; }
    st[25] = acc;                                   // == 4096
  }
  __syncthreads();
  if (threadIdx.x < 25) cur[threadIdx.x] = st[threadIdx.x];
  if (threadIdx.x < 26) starts[b * 32 + threadIdx.x] = st[threadIdx.x];
  __syncthreads();
  for (int i = threadIdx.x; i < BN; i += 256) {
    float x = locs[(b * BN + i) * 2], y = locs[(b * BN + i) * 2 + 1];
    int pos = atomicAdd(&cur[cell_of(x, y)], 1);
    perm[b * BN + pos] = i;
    pack[b * BN + pos] = make_float4(x, y, 0.f, mask[b * BN + i] ? 1.f : 0.f);
  }
}

// -------------------------------------------- fused sparse Sinkhorn (coop) --
// All 6 half-iterations in one cooperative launch; grid.sync() between phases
// (device-scope visibility across XCDs). Same sparse mirror as round 2
// (verified absmax 9.8e-4): finite terms only in 3x3 box; NEG_INF leak rows
// (val == 1e9f exactly) counted per batch into Zc[phase+1], folded into the
// next phase as Z copies of exp(0)=1.
__global__ __launch_bounds__(256) void k_sink_all(
    float4* __restrict__ t_sorted, float4* __restrict__ s_sorted,
    const int* __restrict__ starts_t, const int* __restrict__ starts_s,
    int* __restrict__ Zc) {
  cg::grid_group grid = cg::this_grid();
  const int wid  = (blockIdx.x << 2) + (threadIdx.x >> 6); // 0..4095
  const int lane = threadIdx.x & 63;
  for (int ph = 0; ph < 6; ph++) {
    float4*       own = (ph & 1) ? s_sorted : t_sorted;
    const float4* opp = (ph & 1) ? t_sorted : s_sorted;
    const int*    ost = (ph & 1) ? starts_t : starts_s;
    const int* Zin = Zc + ph * 4;
    int*      Zout = Zc + (ph + 1) * 4;
    const int zero_invalid = (ph & 1);
    for (int row = wid; row < BB * BN; row += 4096) {
      const int b = row >> 12;
      const float4 me = own[row];
      float mrun = -1e30f, srun = 0.f;
      if (me.w != 0.f) {
        const int cell = cell_of(me.x, me.y);
        const int cy = cell / 5, cx = cell % 5;
        const int ry0 = max(cy - 1, 0), ry1 = min(cy + 1, 4);
        const int rx0 = max(cx - 1, 0), rx1 = min(cx + 1, 4);
        for (int ry = ry0; ry <= ry1; ry++) {
          const int r0 = ost[b * 32 + ry * 5 + rx0];
          const int r1 = ost[b * 32 + ry * 5 + rx1 + 1];
          for (int j = r0 + lane; j < r1; j += 64) {
            float4 o = opp[b * BN + j];
            float dx = me.x - o.x, dy = me.y - o.y;
            float d2 = fmaf(dx, dx, dy * dy);
            bool  c  = (d2 < T2) && (o.w != 0.f);
            float t  = c ? fmaf(d2, -INV_EPS, o.z) : -3e30f;  // masked: exp -> 0
            float d  = t - mrun;
            float e  = __expf(-fabsf(d));
            if (d > 0.f) { srun = fmaf(srun, e, 1.f); mrun = t; }
            else         { srun += e; }
          }
        }
      }
      for (int off = 32; off > 0; off >>= 1) {
        float om = __shfl_down(mrun, off);
        float os = __shfl_down(srun, off);
        float nm = fmaxf(mrun, om);
        srun = srun * __expf(mrun - nm) + os * __expf(om - nm);
        mrun = nm;
      }
      if (lane == 0) {
        const int Z = Zin[b];
        float m0 = mrun, s = srun;
        if (Z > 0) {                     // fold leak terms (t == 0, count Z)
          m0 = fmaxf(mrun, 0.f);
          s  = srun * __expf(mrun - m0) + (float)Z * __expf(-m0);
        }
        float val = (s > 0.f) ? -(m0 + logf(s)) : 1.0e9f;
        if (zero_invalid && me.w == 0.f) val = 0.f;
        own[row] = make_float4(me.x, me.y, val, me.w);
        if (val == 1.0e9f) atomicAdd(&Zout[b], 1);
      }
    }
    grid.sync();
  }
}

// ------------------------------------------------- sparse attn @ feats ------
// Block = (batch, cell, 32-target chunk, 128-channel half). Full 3x3 box per
// block flattened into one virtual source range; software-pipelined:
//   - sL/sorg for chunk i+1 live in registers of lanes 0..15 of EVERY wave
//     (shfl-broadcast; no LDS, no barrier)
//   - fL (16src x 32 float4) + attn (16x32) double-buffered; feats global
//     loads for chunk i+1 issued before MAC(i) which hides their latency
//   - ONE __syncthreads per chunk
// No atomics: each block owns out[targets x chalf]; plain float4 stores.
// has_source / target_valid gates are redundant (attn == 0 there exactly).
#define MAXCH 12   // 12*32 = 384 targets/cell upper bound (mean 164, sigma 13)

__global__ __launch_bounds__(256) void k_out(
    const float4* __restrict__ featsF4, const float4* __restrict__ t_sorted,
    const float4* __restrict__ s_sorted, const int* __restrict__ perm_t,
    const int* __restrict__ perm_s, const int* __restrict__ starts_t,
    const int* __restrict__ starts_s, float4* __restrict__ outF4) {
  const int b    = blockIdx.z >> 1;
  const int chO  = (blockIdx.z & 1) << 5;         // float4 channel offset: 0 / 32
  const int cell = blockIdx.y;
  const int t0 = starts_t[b * 32 + cell], t1 = starts_t[b * 32 + cell + 1];
  const int base = t0 + blockIdx.x * 32;
  if (base >= t1) return;                          // uniform early-exit
  const int nt = min(32, t1 - base);

  const int cy = cell / 5, cx = cell % 5;
  const int rx0 = max(cx - 1, 0), rx1 = min(cx + 1, 4);
  int r0[3], len[3];
  #pragma unroll
  for (int k = 0; k < 3; k++) {
    int ry = cy + k - 1;
    if (ry >= 0 && ry <= 4) {
      int a = starts_s[b * 32 + ry * 5 + rx0];
      int e = starts_s[b * 32 + ry * 5 + rx1 + 1];
      r0[k] = a; len[k] = e - a;
    } else { r0[k] = 0; len[k] = 0; }
  }
  const int total   = len[0] + len[1] + len[2];
  const int nchunks = (total + 15) >> 4;

  __shared__ float4 tL[32];                        // x, y, u, tv
  __shared__ int    morg[32];
  __shared__ __align__(16) float  attnL[2][16][32];
  __shared__ __align__(16) float4 fL[2][512];      // [buf][srcRow*32 + c4]

  const int tid  = threadIdx.x;
  const int w    = tid >> 6, lane = tid & 63;
  const int tmg  = tid >> 5, chg = tid & 31;

  if (tid < 32) {
    if (tid < nt) {
      tL[tid]   = t_sorted[b * BN + base + tid];
      morg[tid] = perm_t[b * BN + base + tid];
    } else {
      tL[tid]   = make_float4(0.f, 0.f, 0.f, 0.f); // tv=0 -> attn 0
      morg[tid] = 0;
    }
  }

  float acc[4][4];
  #pragma unroll
  for (int i = 0; i < 4; i++)
    #pragma unroll
    for (int j = 0; j < 4; j++) acc[i][j] = 0.f;

  // --- register-resident source prefetch (lanes 0..15 hold the 16 sources) --
  float4 sreg = make_float4(1e9f, 1e9f, 0.f, 0.f);
  int    sorgreg = 0;
  auto loadS = [&](int chunk) {
    int v  = chunk * 16 + lane;                    // virtual index in box range
    int jj = -1;
    if (v < len[0]) jj = r0[0] + v;
    else {
      v -= len[0];
      if (v < len[1]) jj = r0[1] + v;
      else {
        v -= len[1];
        if (v < len[2]) jj = r0[2] + v;
      }
    }
    if (lane < 16) {
      if (jj >= 0) {
        sreg    = s_sorted[b * BN + jj];
        sorgreg = perm_s[b * BN + jj];
      } else {
        sreg    = make_float4(1e9f, 1e9f, 0.f, 0.f);  // pad: attn==0
        sorgreg = 0;
      }
    }
  };
  float4 greg[2];
  auto issue_loads = [&]() {                       // feats for chunk in sreg
    #pragma unroll
    for (int q = 0; q < 2; q++) {
      int row = (w << 2) + (q << 1) + (lane >> 5); // 0..15
      int so  = __shfl(sorgreg, row);
      greg[q] = featsF4[(((b << 12) + so) << 6) + chO + (lane & 31)];
    }
  };
  auto write_fl = [&](int bi) {
    #pragma unroll
    for (int q = 0; q < 2; q++)
      fL[bi][(w << 7) + (q << 6) + lane] = greg[q];
  };
  auto stage_attn = [&](int bi) {                  // attn for chunk in sreg
    #pragma unroll
    for (int q = 0; q < 2; q++) {
      int e  = tid * 2 + q;
      int nn = e >> 5, tm = e & 31;                // nn in [4w, 4w+4) < 16
      float sx = __shfl(sreg.x, nn);
      float sy = __shfl(sreg.y, nn);
      float sv = __shfl(sreg.z, nn);
      float sw = __shfl(sreg.w, nn);
      float4 t4 = tL[tm];
      float dx = t4.x - sx, dy = t4.y - sy;
      float d2 = fmaf(dx, dx, dy * dy);
      bool  c  = (d2 < T2) && (sw != 0.f) && (t4.w != 0.f);
      attnL[bi][nn][tm] = c ? __expf(fmaf(d2, -INV_EPS, t4.z + sv)) : 0.f;
    }
  };
  auto mac = [&](int bi) {
    #pragma unroll
    for (int nn = 0; nn < 16; nn++) {
      const float4 av = *(const float4*)&attnL[bi][nn][tmg << 2];
      const float4 f  = fL[bi][(nn << 5) + chg];
      #pragma unroll
      for (int i = 0; i < 4; i++) {
        float a = (&av.x)[i];
        acc[i][0] = fmaf(a, f.x, acc[i][0]);
        acc[i][1] = fmaf(a, f.y, acc[i][1]);
        acc[i][2] = fmaf(a, f.z, acc[i][2]);
        acc[i][3] = fmaf(a, f.w, acc[i][3]);
      }
    }
  };

  // --- pipeline prologue ---
  loadS(0);
  __syncthreads();                                 // tL/morg visible
  if (nchunks > 0) {
    issue_loads();
    write_fl(0);
    stage_attn(0);
    loadS(1);
  }
  __syncthreads();

  // --- main loop: 1 barrier per chunk ---
  for (int i = 0; i < nchunks; i++) {
    const int cur = i & 1, nxt = cur ^ 1;
    const bool more = (i + 1) < nchunks;
    if (more) issue_loads();                       // latency hidden by MAC
    mac(cur);
    if (more) {
      write_fl(nxt);
      stage_attn(nxt);
      loadS(i + 2);
    }
    __syncthreads();
  }

  // --- epilogue: plain stores, each output owned by exactly one block ---
  #pragma unroll
  for (int i = 0; i < 4; i++) {
    int tm = (tmg << 2) + i;
    if (tm < nt) {
      outF4[(((b << 12) + morg[tm]) << 6) + chO + chg] =
          make_float4(acc[i][0], acc[i][1], acc[i][2], acc[i][3]);
    }
  }
}

// ----------------------------------------------------------------- launch ---
extern "C" void kernel_launch(void* const* d_in, const int* in_sizes, int n_in,
                              void* d_out, int out_size, void* d_ws, size_t ws_size,
                              hipStream_t stream) {
  const float* feats = (const float*)d_in[0];   // [B,N,C] f32
  const float* slocs = (const float*)d_in[1];   // [B,N,2] f32
  const float* tlocs = (const float*)d_in[2];   // [B,M,2] f32
  const int*   smask = (const int*)d_in[3];     // [B,N] int32 (bool)
  const int*   tmask = (const int*)d_in[4];     // [B,M] int32 (bool)

  char* ws = (char*)d_ws;                       // ~660 KB used
  int*    counts_t = (int*)(ws);                //   512 B
  int*    counts_s = (int*)(ws + 512);          //   512 B
  int*    Zc       = (int*)(ws + 1024);         //   7 slots x 4 batches
  int*    starts_t = (int*)(ws + 2048);         //   512 B
  int*    starts_s = (int*)(ws + 2560);         //   512 B
  int*    perm_t   = (int*)(ws + 4096);         //   64 KB
  int*    perm_s   = (int*)(ws + 69632);        //   64 KB
  float4* s_sorted = (float4*)(ws + 135168);    //  256 KB (x,y,v,sv) cell-sorted
  float4* t_sorted = (float4*)(ws + 397312);    //  256 KB (x,y,u,tv) cell-sorted

  hipMemsetAsync(ws, 0, 2048, stream);          // zero cell counters + Z slots
  k_count<<<128, 256, 0, stream>>>(tlocs, slocs, counts_t, counts_s);
  k_scan_scatter<<<8, 256, 0, stream>>>(tlocs, slocs, tmask, smask,
                                        counts_t, counts_s, starts_t, starts_s,
                                        perm_t, perm_s, t_sorted, s_sorted);
  void* args[] = {&t_sorted, &s_sorted, &starts_t, &starts_s, &Zc};
  hipLaunchCooperativeKernel((void*)k_sink_all, dim3(1024), dim3(256), args, 0, stream);
  k_out<<<dim3(MAXCH, 25, BB * 2), 256, 0, stream>>>(
      (const float4*)feats, t_sorted, s_sorted, perm_t, perm_s,
      starts_t, starts_s, (float4*)d_out);
}

// Round 4
// 771.881 us; speedup vs baseline: 2.0654x; 2.0654x over previous
//
#include <hip/hip_runtime.h>
#include <math.h>

// Problem constants (reference: B,N,M,C = 4,4096,4096,256)
#define BB 4
#define BN 4096          // N == M == 4096
constexpr float T2      = 0.04f;                     // DIST_THRESH^2
constexpr float INV_EPS = (float)(1.0 / 0.01000001); // 1/(EPSILON + 1e-8)

__device__ __forceinline__ int cell_of(float x, float y) {
  int cx = (int)(x * 5.0f); cx = cx < 0 ? 0 : (cx > 4 ? 4 : cx);
  int cy = (int)(y * 5.0f); cy = cy < 0 ? 0 : (cy > 4 ? 4 : cy);
  return cy * 5 + cx;
}

// ---------------------------------------------------------------- binning ---
__global__ void k_count(const float* __restrict__ tlocs, const float* __restrict__ slocs,
                        int* __restrict__ counts_t, int* __restrict__ counts_s) {
  int gid = blockIdx.x * 256 + threadIdx.x;       // covers B*(M+N) = 32768
  if (gid < BB * BN) {
    int b = gid >> 12;
    atomicAdd(&counts_t[b * 32 + cell_of(tlocs[gid * 2], tlocs[gid * 2 + 1])], 1);
  } else {
    int g = gid - BB * BN;
    int b = g >> 12;
    atomicAdd(&counts_s[b * 32 + cell_of(slocs[g * 2], slocs[g * 2 + 1])], 1);
  }
}

// Scan 25 cells, scatter indices AND build cell-sorted packs (x, y, 0, valid).
__global__ void k_scan_scatter(const float* __restrict__ tlocs, const float* __restrict__ slocs,
                               const int* __restrict__ tmask, const int* __restrict__ smask,
                               const int* __restrict__ counts_t, const int* __restrict__ counts_s,
                               int* __restrict__ starts_t, int* __restrict__ starts_s,
                               int* __restrict__ perm_t, int* __restrict__ perm_s,
                               float4* __restrict__ t_sorted, float4* __restrict__ s_sorted) {
  const int which = blockIdx.x & 1, b = blockIdx.x >> 1;   // grid = 2*B
  const float* locs = which ? slocs : tlocs;
  const int*   mask = which ? smask : tmask;
  const int* counts = which ? counts_s : counts_t;
  int* starts       = which ? starts_s : starts_t;
  int* perm         = which ? perm_s : perm_t;
  float4* pack      = which ? s_sorted : t_sorted;
  __shared__ int st[26];
  __shared__ int cur[25];
  if (threadIdx.x == 0) {
    int acc = 0;
    for (int c = 0; c < 25; c++) { st[c] = acc; acc += counts[b * 32 + c]; }
    st[25] = acc;                                   // == 4096
  }
  __syncthreads();
  if (threadIdx.x < 25) cur[threadIdx.x] = st[threadIdx.x];
  if (threadIdx.x < 26) starts[b * 32 + threadIdx.x] = st[threadIdx.x];
  __syncthreads();
  for (int i = threadIdx.x; i < BN; i += 256) {
    float x = locs[(b * BN + i) * 2], y = locs[(b * BN + i) * 2 + 1];
    int pos = atomicAdd(&cur[cell_of(x, y)], 1);
    perm[b * BN + pos] = i;
    pack[b * BN + pos] = make_float4(x, y, 0.f, mask[b * BN + i] ? 1.f : 0.f);
  }
}

// ------------------------------------------------------ sparse Sinkhorn -----
// One wave per row, 16384 waves (64 waves/CU). Latency fix vs r2/r3: the
// candidate loop is unrolled x8 with a batched register prefetch -- 8
// independent global_load_dwordx4 issued before any dependent math, so each
// cell-row segment (~370 candidates ~= 6 wave-iters) exposes ONE load latency
// instead of six. Same verified sparse mirror semantics (absmax 9.8e-4):
// finite terms only in 3x3 box; NEG_INF leak rows counted into Zout, folded
// into the next phase as Z copies of exp(0)=1.
#define UNR 8
__global__ __launch_bounds__(256) void k_sink(const float4* __restrict__ opp,
                                              float4* __restrict__ own,
                                              const int* __restrict__ opp_starts,
                                              const int* __restrict__ Zin,
                                              int* __restrict__ Zout,
                                              int zero_invalid) {
  const int row  = blockIdx.x * 4 + (threadIdx.x >> 6);    // 0..16383
  const int b    = row >> 12;
  const int lane = threadIdx.x & 63;
  const float4 me = own[row];
  float mrun = -1e30f, srun = 0.f;
  if (me.w != 0.f) {                                       // invalid rows: no finite terms
    const int cell = cell_of(me.x, me.y);
    const int cy = cell / 5, cx = cell % 5;
    const int ry0 = max(cy - 1, 0), ry1 = min(cy + 1, 4);
    const int rx0 = max(cx - 1, 0), rx1 = min(cx + 1, 4);
    const float4* oppB = opp + b * BN;
    for (int ry = ry0; ry <= ry1; ry++) {
      const int r0 = opp_starts[b * 32 + ry * 5 + rx0];
      const int r1 = opp_starts[b * 32 + ry * 5 + rx1 + 1];  // contiguous row-major cells
      for (int base = r0 + lane; base < r1; base += 64 * UNR) {
        float4 buf[UNR];
        #pragma unroll
        for (int u = 0; u < UNR; u++) {                    // 8 loads in flight
          int j = base + u * 64;
          if (j < r1) buf[u] = oppB[j];
        }
        #pragma unroll
        for (int u = 0; u < UNR; u++) {
          int j = base + u * 64;
          if (j < r1) {
            float4 o = buf[u];
            float dx = me.x - o.x, dy = me.y - o.y;
            float d2 = fmaf(dx, dx, dy * dy);
            bool  c  = (d2 < T2) && (o.w != 0.f);
            float t  = c ? fmaf(d2, -INV_EPS, o.z) : -3e30f;  // masked: exp -> 0
            float d  = t - mrun;
            float e  = __expf(-fabsf(d));
            if (d > 0.f) { srun = fmaf(srun, e, 1.f); mrun = t; }
            else         { srun += e; }
          }
        }
      }
    }
  }
  for (int off = 32; off > 0; off >>= 1) {
    float om = __shfl_down(mrun, off);
    float os = __shfl_down(srun, off);
    float nm = fmaxf(mrun, om);
    srun = srun * __expf(mrun - nm) + os * __expf(om - nm);
    mrun = nm;
  }
  if (lane == 0) {
    const int Z = Zin[b];
    float m0 = mrun, s = srun;
    if (Z > 0) {                     // fold leak terms (t == 0, count Z)
      m0 = fmaxf(mrun, 0.f);
      s  = srun * __expf(mrun - m0) + (float)Z * __expf(-m0);
    }
    float val = (s > 0.f) ? -(m0 + logf(s)) : 1.0e9f;      // empty row -> exactly 1e9f
    if (zero_invalid && me.w == 0.f) val = 0.f;
    own[row] = make_float4(me.x, me.y, val, me.w);
    if (val == 1.0e9f) atomicAdd(&Zout[b], 1);
  }
}

// ------------------------------------------------- sparse attn @ feats ------
// Unchanged from round 3 (so its duration finally shows in counters).
// Block = (batch, cell, 32-target chunk, 128-channel half); full 3x3 box per
// block; software-pipelined with 1 barrier per 16-source chunk; no atomics.
#define MAXCH 12   // 12*32 = 384 targets/cell upper bound (mean 164, sigma 13)

__global__ __launch_bounds__(256) void k_out(
    const float4* __restrict__ featsF4, const float4* __restrict__ t_sorted,
    const float4* __restrict__ s_sorted, const int* __restrict__ perm_t,
    const int* __restrict__ perm_s, const int* __restrict__ starts_t,
    const int* __restrict__ starts_s, float4* __restrict__ outF4) {
  const int b    = blockIdx.z >> 1;
  const int chO  = (blockIdx.z & 1) << 5;         // float4 channel offset: 0 / 32
  const int cell = blockIdx.y;
  const int t0 = starts_t[b * 32 + cell], t1 = starts_t[b * 32 + cell + 1];
  const int base = t0 + blockIdx.x * 32;
  if (base >= t1) return;                          // uniform early-exit
  const int nt = min(32, t1 - base);

  const int cy = cell / 5, cx = cell % 5;
  const int rx0 = max(cx - 1, 0), rx1 = min(cx + 1, 4);
  int r0[3], len[3];
  #pragma unroll
  for (int k = 0; k < 3; k++) {
    int ry = cy + k - 1;
    if (ry >= 0 && ry <= 4) {
      int a = starts_s[b * 32 + ry * 5 + rx0];
      int e = starts_s[b * 32 + ry * 5 + rx1 + 1];
      r0[k] = a; len[k] = e - a;
    } else { r0[k] = 0; len[k] = 0; }
  }
  const int total   = len[0] + len[1] + len[2];
  const int nchunks = (total + 15) >> 4;

  __shared__ float4 tL[32];                        // x, y, u, tv
  __shared__ int    morg[32];
  __shared__ __align__(16) float  attnL[2][16][32];
  __shared__ __align__(16) float4 fL[2][512];      // [buf][srcRow*32 + c4]

  const int tid  = threadIdx.x;
  const int w    = tid >> 6, lane = tid & 63;
  const int tmg  = tid >> 5, chg = tid & 31;

  if (tid < 32) {
    if (tid < nt) {
      tL[tid]   = t_sorted[b * BN + base + tid];
      morg[tid] = perm_t[b * BN + base + tid];
    } else {
      tL[tid]   = make_float4(0.f, 0.f, 0.f, 0.f); // tv=0 -> attn 0
      morg[tid] = 0;
    }
  }

  float acc[4][4];
  #pragma unroll
  for (int i = 0; i < 4; i++)
    #pragma unroll
    for (int j = 0; j < 4; j++) acc[i][j] = 0.f;

  // --- register-resident source prefetch (lanes 0..15 hold the 16 sources) --
  float4 sreg = make_float4(1e9f, 1e9f, 0.f, 0.f);
  int    sorgreg = 0;
  auto loadS = [&](int chunk) {
    int v  = chunk * 16 + lane;                    // virtual index in box range
    int jj = -1;
    if (v < len[0]) jj = r0[0] + v;
    else {
      v -= len[0];
      if (v < len[1]) jj = r0[1] + v;
      else {
        v -= len[1];
        if (v < len[2]) jj = r0[2] + v;
      }
    }
    if (lane < 16) {
      if (jj >= 0) {
        sreg    = s_sorted[b * BN + jj];
        sorgreg = perm_s[b * BN + jj];
      } else {
        sreg    = make_float4(1e9f, 1e9f, 0.f, 0.f);  // pad: attn==0
        sorgreg = 0;
      }
    }
  };
  float4 greg[2];
  auto issue_loads = [&]() {                       // feats for chunk in sreg
    #pragma unroll
    for (int q = 0; q < 2; q++) {
      int row = (w << 2) + (q << 1) + (lane >> 5); // 0..15
      int so  = __shfl(sorgreg, row);
      greg[q] = featsF4[(((b << 12) + so) << 6) + chO + (lane & 31)];
    }
  };
  auto write_fl = [&](int bi) {
    #pragma unroll
    for (int q = 0; q < 2; q++)
      fL[bi][(w << 7) + (q << 6) + lane] = greg[q];
  };
  auto stage_attn = [&](int bi) {                  // attn for chunk in sreg
    #pragma unroll
    for (int q = 0; q < 2; q++) {
      int e  = tid * 2 + q;
      int nn = e >> 5, tm = e & 31;                // nn in [4w, 4w+4) < 16
      float sx = __shfl(sreg.x, nn);
      float sy = __shfl(sreg.y, nn);
      float sv = __shfl(sreg.z, nn);
      float sw = __shfl(sreg.w, nn);
      float4 t4 = tL[tm];
      float dx = t4.x - sx, dy = t4.y - sy;
      float d2 = fmaf(dx, dx, dy * dy);
      bool  c  = (d2 < T2) && (sw != 0.f) && (t4.w != 0.f);
      attnL[bi][nn][tm] = c ? __expf(fmaf(d2, -INV_EPS, t4.z + sv)) : 0.f;
    }
  };
  auto mac = [&](int bi) {
    #pragma unroll
    for (int nn = 0; nn < 16; nn++) {
      const float4 av = *(const float4*)&attnL[bi][nn][tmg << 2];
      const float4 f  = fL[bi][(nn << 5) + chg];
      #pragma unroll
      for (int i = 0; i < 4; i++) {
        float a = (&av.x)[i];
        acc[i][0] = fmaf(a, f.x, acc[i][0]);
        acc[i][1] = fmaf(a, f.y, acc[i][1]);
        acc[i][2] = fmaf(a, f.z, acc[i][2]);
        acc[i][3] = fmaf(a, f.w, acc[i][3]);
      }
    }
  };

  // --- pipeline prologue ---
  loadS(0);
  __syncthreads();                                 // tL/morg visible
  if (nchunks > 0) {
    issue_loads();
    write_fl(0);
    stage_attn(0);
    loadS(1);
  }
  __syncthreads();

  // --- main loop: 1 barrier per chunk ---
  for (int i = 0; i < nchunks; i++) {
    const int cur = i & 1, nxt = cur ^ 1;
    const bool more = (i + 1) < nchunks;
    if (more) issue_loads();                       // latency hidden by MAC
    mac(cur);
    if (more) {
      write_fl(nxt);
      stage_attn(nxt);
      loadS(i + 2);
    }
    __syncthreads();
  }

  // --- epilogue: plain stores, each output owned by exactly one block ---
  #pragma unroll
  for (int i = 0; i < 4; i++) {
    int tm = (tmg << 2) + i;
    if (tm < nt) {
      outF4[(((b << 12) + morg[tm]) << 6) + chO + chg] =
          make_float4(acc[i][0], acc[i][1], acc[i][2], acc[i][3]);
    }
  }
}

// ----------------------------------------------------------------- launch ---
extern "C" void kernel_launch(void* const* d_in, const int* in_sizes, int n_in,
                              void* d_out, int out_size, void* d_ws, size_t ws_size,
                              hipStream_t stream) {
  const float* feats = (const float*)d_in[0];   // [B,N,C] f32
  const float* slocs = (const float*)d_in[1];   // [B,N,2] f32
  const float* tlocs = (const float*)d_in[2];   // [B,M,2] f32
  const int*   smask = (const int*)d_in[3];     // [B,N] int32 (bool)
  const int*   tmask = (const int*)d_in[4];     // [B,M] int32 (bool)

  char* ws = (char*)d_ws;                       // ~660 KB used
  int*    counts_t = (int*)(ws);                //   512 B
  int*    counts_s = (int*)(ws + 512);          //   512 B
  int*    Zc       = (int*)(ws + 1024);         //   7 slots x 4 batches
  int*    starts_t = (int*)(ws + 2048);         //   512 B
  int*    starts_s = (int*)(ws + 2560);         //   512 B
  int*    perm_t   = (int*)(ws + 4096);         //   64 KB
  int*    perm_s   = (int*)(ws + 69632);        //   64 KB
  float4* s_sorted = (float4*)(ws + 135168);    //  256 KB (x,y,v,sv) cell-sorted
  float4* t_sorted = (float4*)(ws + 397312);    //  256 KB (x,y,u,tv) cell-sorted

  hipMemsetAsync(ws, 0, 2048, stream);          // zero cell counters + Z slots
  k_count<<<128, 256, 0, stream>>>(tlocs, slocs, counts_t, counts_s);
  k_scan_scatter<<<8, 256, 0, stream>>>(tlocs, slocs, tmask, smask,
                                        counts_t, counts_s, starts_t, starts_s,
                                        perm_t, perm_s, t_sorted, s_sorted);
  for (int it = 0; it < 3; it++) {
    // u-update: Zin = leak count of current v (slot 0 = zeros for it==0)
    k_sink<<<4096, 256, 0, stream>>>(s_sorted, t_sorted, starts_s,
                                     Zc + (it == 0 ? 0 : (2 * it) * 4),
                                     Zc + (2 * it + 1) * 4, 0);
    // v-update: Zin = leak count of u just written
    k_sink<<<4096, 256, 0, stream>>>(t_sorted, s_sorted, starts_t,
                                     Zc + (2 * it + 1) * 4,
                                     Zc + (2 * it + 2) * 4, 1);
  }
  k_out<<<dim3(MAXCH, 25, BB * 2), 256, 0, stream>>>(
      (const float4*)feats, t_sorted, s_sorted, perm_t, perm_s,
      starts_t, starts_s, (float4*)d_out);
}